// Round 1
// baseline (193.672 us; speedup 1.0000x reference)
//
#include <hip/hip_runtime.h>

#define N_NODES 65536
#define B_G     64
#define NPG     1024
#define KC      128
#define DIN     128
#define E_EDGES 1048576
#define EPG     16384
#define CSTRIDE (EPG + NPG)       // per-graph CSR slots (even-padded offsets)

typedef __attribute__((ext_vector_type(8))) short short8;
typedef __attribute__((ext_vector_type(4))) float floatx4;

static __device__ __forceinline__ short f2bf(float x) {
    unsigned u = __float_as_uint(x);
    unsigned r = (u + 0x7FFF + ((u >> 16) & 1)) >> 16;
    return (short)r;
}
static __device__ __forceinline__ unsigned pack2(float a, float b) {
    return (unsigned)(unsigned short)f2bf(a) | ((unsigned)(unsigned short)f2bf(b) << 16);
}

// ================ setup_all:
//   blocks 0..63    : per-graph CSR build (hist -> block scan -> scatter, all in LDS)
//   blocks 64..8383 : wt / feaT / h_bf conversions
__global__ __launch_bounds__(256) void setup_all(
    const float* __restrict__ Wself, const float* __restrict__ Wneigh,
    const float* __restrict__ fea, const float* __restrict__ h,
    const int* __restrict__ esrc, const int* __restrict__ edst,
    short* __restrict__ wt, short* __restrict__ feaT, short* __restrict__ h_bf,
    int* __restrict__ offs, int* __restrict__ deg, unsigned short* __restrict__ csr)
{
    int bid = blockIdx.x;
    int tid = threadIdx.x;
    if (bid < B_G) {
        // ---- per-graph CSR build: one block per graph
        __shared__ int cnt[NPG];
        __shared__ int cur[NPG];
        __shared__ int sc[256];
        int g = bid;
        int gbase = g << 10;
        for (int i = tid; i < NPG; i += 256) cnt[i] = 0;
        __syncthreads();
        const int* ed = edst + (size_t)g * EPG;
        const int* es = esrc + (size_t)g * EPG;
#pragma unroll 4
        for (int it = 0; it < EPG / 256; it++)
            atomicAdd(&cnt[ed[it * 256 + tid] - gbase], 1);
        __syncthreads();
        // each thread owns 4 consecutive bins; pad each node's slot count to even
        int c[4], p[4];
        int local = 0;
#pragma unroll
        for (int i = 0; i < 4; i++) {
            c[i] = cnt[tid * 4 + i];
            p[i] = (c[i] + 1) & ~1;
            local += p[i];
        }
        sc[tid] = local;
        __syncthreads();
        for (int off = 1; off < 256; off <<= 1) {
            int v = sc[tid];
            int vv = (tid >= off) ? sc[tid - off] : 0;
            __syncthreads();
            sc[tid] = v + vv;
            __syncthreads();
        }
        int run = sc[tid] - local;   // exclusive prefix (even)
#pragma unroll
        for (int i = 0; i < 4; i++) {
            int node = gbase + tid * 4 + i;
            offs[node] = run;
            deg[node] = c[i];
            cur[tid * 4 + i] = run;
            run += p[i];
        }
        __syncthreads();
        unsigned short* cg = csr + (size_t)g * CSTRIDE;
#pragma unroll 4
        for (int it = 0; it < EPG / 256; it++) {
            int e = it * 256 + tid;
            int d = ed[e] - gbase;
            int s = es[e] - gbase;
            int pos = atomicAdd(&cur[d], 1);
            cg[pos] = (unsigned short)s;
        }
    } else {
        // ---- conversions: 8320 blocks x 256 threads
        long idx = (long)(bid - B_G) * 256 + tid;
        if (idx < 32768) {
            int n = (int)(idx >> 8), k = (int)(idx & 255);
            float v = (k < 128) ? Wself[k * 128 + n] : Wneigh[(k - 128) * 128 + n];
            wt[idx] = f2bf(v);
        } else if (idx < 32768 + 1048576) {
            long fi = idx - 32768;
            int g = (int)(fi >> 14), d = (int)((fi >> 7) & 127), k = (int)(fi & 127);
            feaT[fi] = f2bf(fea[((long)g * 128 + k) * 128 + d]);
        } else {
            long gi = idx - 32768 - 1048576;   // 8 floats per item
            const float4* hp = (const float4*)h + gi * 2;
            float4 a = hp[0], b4 = hp[1];
            uint4 w;
            w.x = pack2(a.x, a.y);
            w.y = pack2(a.z, a.w);
            w.z = pack2(b4.x, b4.y);
            w.w = pack2(b4.z, b4.w);
            ((uint4*)h_bf)[gi] = w;
        }
    }
}

// ================ aggregation (pull, bf16): one wave per node,
// 2 edges per gather instruction (lanes 0-31 edge A, 32-63 edge B)
__global__ __launch_bounds__(256) void agg_kernel(
    const short* __restrict__ h_bf, const unsigned short* __restrict__ csr,
    const int* __restrict__ offs, const int* __restrict__ deg,
    short* __restrict__ neigh)
{
    int g = blockIdx.x & 63;
    int chunk = blockIdx.x >> 6;
    int wave = threadIdx.x >> 6, lane = threadIdx.x & 63;
    int local = chunk * 4 + wave;
    int node = g * NPG + local;
    int start = offs[node];
    int m = deg[node];
    const unsigned short* lst = csr + (size_t)g * CSTRIDE + start;
    const uint2* rows = (const uint2*)h_bf + (size_t)g * NPG * 32;  // 32 uint2 / row
    int l31 = lane & 31;
    int hi = lane >> 5;
    float s0 = 0.f, s1 = 0.f, s2 = 0.f, s3 = 0.f;
    int pairs = m >> 1;
    int p = 0;
    for (; p + 4 <= pairs; p += 4) {
        unsigned pp[4];
#pragma unroll
        for (int u = 0; u < 4; u++) pp[u] = *(const unsigned*)(lst + 2 * (p + u));
        uint2 v[4];
#pragma unroll
        for (int u = 0; u < 4; u++) {
            int s = hi ? (int)(pp[u] >> 16) : (int)(pp[u] & 0xffff);
            v[u] = rows[s * 32 + l31];
        }
#pragma unroll
        for (int u = 0; u < 4; u++) {
            s0 += __uint_as_float(v[u].x << 16);
            s1 += __uint_as_float(v[u].x & 0xffff0000u);
            s2 += __uint_as_float(v[u].y << 16);
            s3 += __uint_as_float(v[u].y & 0xffff0000u);
        }
    }
    for (; p < pairs; p++) {
        unsigned pp = *(const unsigned*)(lst + 2 * p);
        int s = hi ? (int)(pp >> 16) : (int)(pp & 0xffff);
        uint2 vv = rows[s * 32 + l31];
        s0 += __uint_as_float(vv.x << 16);
        s1 += __uint_as_float(vv.x & 0xffff0000u);
        s2 += __uint_as_float(vv.y << 16);
        s3 += __uint_as_float(vv.y & 0xffff0000u);
    }
    if (m & 1) {
        int s = lst[m - 1];
        if (!hi) {
            uint2 vv = rows[s * 32 + l31];
            s0 += __uint_as_float(vv.x << 16);
            s1 += __uint_as_float(vv.x & 0xffff0000u);
            s2 += __uint_as_float(vv.y << 16);
            s3 += __uint_as_float(vv.y & 0xffff0000u);
        }
    }
    s0 += __shfl_xor(s0, 32, 64);
    s1 += __shfl_xor(s1, 32, 64);
    s2 += __shfl_xor(s2, 32, 64);
    s3 += __shfl_xor(s3, 32, 64);
    if (!hi) {
        float invd = 1.0f / fmaxf((float)m, 1.0f);
        uint2 w;
        w.x = pack2(s0 * invd, s1 * invd);
        w.y = pack2(s2 * invd, s3 * invd);
        ((uint2*)neigh)[(size_t)node * 32 + l31] = w;
    }
}

// ================ fused: assign = softmax(relu([h_bf|neigh] @ wt^T + b));
//                  out = assign @ fea   (P kept on-chip via LDS round-trip)
__global__ __launch_bounds__(256) void fused_kernel(
    const short* __restrict__ h_bf, const short* __restrict__ neigh,
    const short* __restrict__ wt, const float* __restrict__ bias,
    const short* __restrict__ feaT, float* __restrict__ out)
{
    __shared__ __align__(16) char smem[50688];
    short* lds_a = (short*)smem;            // phase1: 128x72
    short* lds_b = lds_a + 128 * 72;        // phase1: 128x72
    short* ldsP  = (short*)smem;            // phase2: 128x132 (overlaps phase1)
    short* ldsB2 = ldsP + 128 * 132;        // phase2: 64x132

    int tid = threadIdx.x;
    int tile_m = blockIdx.x * 128;
    int g = tile_m >> 10;
    int wave = tid >> 6, lane = tid & 63;
    int l15 = lane & 15, quad = lane >> 4;

    floatx4 zz = {0.f, 0.f, 0.f, 0.f};
    floatx4 acc[2][8];
#pragma unroll
    for (int i = 0; i < 2; i++)
#pragma unroll
        for (int j = 0; j < 8; j++) acc[i][j] = zz;

    int row_s = tid >> 1;
    int c0 = (tid & 1) * 32;

    // ---- GEMM1: logits = [h_bf | neigh] @ wt^T, K=256 in 4 chunks of 64
    for (int kk = 0; kk < 4; kk++) {
        const short* src = (kk < 2)
            ? h_bf + (size_t)(tile_m + row_s) * DIN + kk * 64 + c0
            : neigh + (size_t)(tile_m + row_s) * DIN + (kk - 2) * 64 + c0;
        short* dsta = lds_a + row_s * 72 + c0;
#pragma unroll
        for (int i = 0; i < 32; i += 8)
            *reinterpret_cast<short8*>(dsta + i) = *reinterpret_cast<const short8*>(src + i);
        const short* srcb = wt + row_s * 256 + kk * 64 + c0;
        short* dstb = lds_b + row_s * 72 + c0;
#pragma unroll
        for (int i = 0; i < 32; i += 8)
            *reinterpret_cast<short8*>(dstb + i) = *reinterpret_cast<const short8*>(srcb + i);
        __syncthreads();
#pragma unroll
        for (int ks = 0; ks < 2; ks++) {
            short8 af[2];
#pragma unroll
            for (int rb = 0; rb < 2; rb++) {
                int m = wave * 32 + rb * 16 + l15;
                af[rb] = *reinterpret_cast<const short8*>(lds_a + m * 72 + ks * 32 + quad * 8);
            }
#pragma unroll
            for (int cb = 0; cb < 8; cb++) {
                int n = cb * 16 + l15;
                short8 bf = *reinterpret_cast<const short8*>(lds_b + n * 72 + ks * 32 + quad * 8);
                acc[0][cb] = __builtin_amdgcn_mfma_f32_16x16x32_bf16(af[0], bf, acc[0][cb], 0, 0, 0);
                acc[1][cb] = __builtin_amdgcn_mfma_f32_16x16x32_bf16(af[1], bf, acc[1][cb], 0, 0, 0);
            }
        }
        __syncthreads();
    }

    // ---- softmax(relu(+bias)) in regs; P -> LDS (bf16, stride 132)
    float bv[8];
#pragma unroll
    for (int cb = 0; cb < 8; cb++) bv[cb] = bias[cb * 16 + l15];

#pragma unroll
    for (int rb = 0; rb < 2; rb++) {
#pragma unroll
        for (int v = 0; v < 4; v++) {
            float x[8];
            float m = -1e30f;
#pragma unroll
            for (int cb = 0; cb < 8; cb++) {
                float t = acc[rb][cb][v] + bv[cb];
                t = fmaxf(t, 0.f);
                x[cb] = t;
                m = fmaxf(m, t);
            }
#pragma unroll
            for (int off = 1; off < 16; off <<= 1) m = fmaxf(m, __shfl_xor(m, off, 64));
            float s = 0.f;
#pragma unroll
            for (int cb = 0; cb < 8; cb++) { x[cb] = __expf(x[cb] - m); s += x[cb]; }
#pragma unroll
            for (int off = 1; off < 16; off <<= 1) s += __shfl_xor(s, off, 64);
            float inv = 1.0f / s;
            int row = wave * 32 + rb * 16 + quad * 4 + v;   // local row
#pragma unroll
            for (int cb = 0; cb < 8; cb++)
                ldsP[row * 132 + cb * 16 + l15] = f2bf(x[cb] * inv);
        }
    }

    // ---- GEMM2: out = P @ fea[g], feaT staged in two 64-row halves
    floatx4 oacc[2][8];
#pragma unroll
    for (int i = 0; i < 2; i++)
#pragma unroll
        for (int j = 0; j < 8; j++) oacc[i][j] = zz;

    int r2 = tid >> 2;            // 0..63
    int c2 = (tid & 3) * 32;      // 0..96
    short8 pf[2][4];

    for (int half = 0; half < 2; half++) {
        if (half) __syncthreads();   // protect previous-half B reads
        const short* srcb = feaT + ((size_t)g * 128 + half * 64 + r2) * 128 + c2;
        short* dstb = ldsB2 + r2 * 132 + c2;
#pragma unroll
        for (int i = 0; i < 32; i += 8)
            *reinterpret_cast<short8*>(dstb + i) = *reinterpret_cast<const short8*>(srcb + i);
        __syncthreads();
        if (half == 0) {
#pragma unroll
            for (int rb = 0; rb < 2; rb++)
#pragma unroll
                for (int ks = 0; ks < 4; ks++)
                    pf[rb][ks] = *reinterpret_cast<const short8*>(
                        ldsP + (wave * 32 + rb * 16 + l15) * 132 + ks * 32 + quad * 8);
        }
#pragma unroll
        for (int cb2 = 0; cb2 < 4; cb2++) {
            int cb = half * 4 + cb2;
#pragma unroll
            for (int ks = 0; ks < 4; ks++) {
                short8 bf = *reinterpret_cast<const short8*>(
                    ldsB2 + (cb2 * 16 + l15) * 132 + ks * 32 + quad * 8);
                oacc[0][cb] = __builtin_amdgcn_mfma_f32_16x16x32_bf16(pf[0][ks], bf, oacc[0][cb], 0, 0, 0);
                oacc[1][cb] = __builtin_amdgcn_mfma_f32_16x16x32_bf16(pf[1][ks], bf, oacc[1][cb], 0, 0, 0);
            }
        }
    }

#pragma unroll
    for (int rb = 0; rb < 2; rb++)
#pragma unroll
        for (int v = 0; v < 4; v++) {
            int row = tile_m + wave * 32 + rb * 16 + quad * 4 + v;
#pragma unroll
            for (int cb = 0; cb < 8; cb++)
                out[(size_t)row * 128 + cb * 16 + l15] = oacc[rb][cb][v];
        }
}

extern "C" void kernel_launch(void* const* d_in, const int* in_sizes, int n_in,
                              void* d_out, int out_size, void* d_ws, size_t ws_size,
                              hipStream_t stream) {
    const float* h      = (const float*)d_in[0];
    const float* fea    = (const float*)d_in[1];
    const float* Wself  = (const float*)d_in[2];
    const float* Wneigh = (const float*)d_in[3];
    const float* bias   = (const float*)d_in[4];
    const int*   esrc   = (const int*)d_in[5];
    const int*   edst   = (const int*)d_in[6];
    float* out = (float*)d_out;

    char* ws = (char*)d_ws;
    short* h_bf = (short*)ws;
    size_t off = (size_t)N_NODES * DIN * sizeof(short);                       // 16 MB
    short* neigh = (short*)(ws + off); off += (size_t)N_NODES * DIN * sizeof(short);   // 16 MB
    short* wt    = (short*)(ws + off); off += (size_t)128 * 256 * sizeof(short);       // 64 KB
    short* feaT  = (short*)(ws + off); off += (size_t)B_G * 128 * 128 * sizeof(short); // 2 MB
    unsigned short* csr = (unsigned short*)(ws + off); off += (size_t)B_G * CSTRIDE * sizeof(short); // 2.2 MB
    int* offs = (int*)(ws + off); off += (size_t)N_NODES * sizeof(int);       // 256 KB
    int* deg  = (int*)(ws + off);                                             // 256 KB

    // setup_all grid: 64 CSR blocks + (32768 + 1048576 + 1048576)/256 = 8320 conv blocks
    setup_all<<<B_G + 8320, 256, 0, stream>>>(Wself, Wneigh, fea, h, esrc, edst,
                                              wt, feaT, h_bf, offs, deg, csr);
    agg_kernel<<<256 * B_G, 256, 0, stream>>>(h_bf, csr, offs, deg, neigh);
    fused_kernel<<<N_NODES / 128, 256, 0, stream>>>(h_bf, neigh, wt, bias, feaT, out);
}

// Round 2
// 182.513 us; speedup vs baseline: 1.0611x; 1.0611x over previous
//
#include <hip/hip_runtime.h>

#define N_NODES 65536
#define B_G     64
#define NPG     1024
#define KC      128
#define DIN     128
#define E_EDGES 1048576
#define EPG     16384
#define CSTRIDE (EPG + NPG)       // per-graph CSR slots (even-padded offsets)

typedef __attribute__((ext_vector_type(8))) short short8;
typedef __attribute__((ext_vector_type(4))) float floatx4;

static __device__ __forceinline__ short f2bf(float x) {
    unsigned u = __float_as_uint(x);
    unsigned r = (u + 0x7FFF + ((u >> 16) & 1)) >> 16;
    return (short)r;
}
static __device__ __forceinline__ unsigned pack2(float a, float b) {
    return (unsigned)(unsigned short)f2bf(a) | ((unsigned)(unsigned short)f2bf(b) << 16);
}

// ================ setup_all (1024 threads/block):
//   blocks 0..63    : per-graph CSR build (hist -> block scan -> scatter, all in LDS)
//                     16 hist iters + 10-step scan + 16 scatter iters
//   blocks 64..2143 : wt / feaT / h_bf conversions
__global__ __launch_bounds__(1024) void setup_all(
    const float* __restrict__ Wself, const float* __restrict__ Wneigh,
    const float* __restrict__ fea, const float* __restrict__ h,
    const int* __restrict__ esrc, const int* __restrict__ edst,
    short* __restrict__ wt, short* __restrict__ feaT, short* __restrict__ h_bf,
    int* __restrict__ offs, int* __restrict__ deg, unsigned short* __restrict__ csr)
{
    int bid = blockIdx.x;
    int tid = threadIdx.x;
    if (bid < B_G) {
        // ---- per-graph CSR build: one 1024-thread block per graph, 1 bin/thread
        __shared__ int cnt[NPG];
        __shared__ int cur[NPG];
        int g = bid;
        int gbase = g << 10;
        cnt[tid] = 0;
        __syncthreads();
        const int* ed = edst + (size_t)g * EPG;
        const int* es = esrc + (size_t)g * EPG;
#pragma unroll 8
        for (int it = 0; it < EPG / 1024; it++)
            atomicAdd(&cnt[ed[it * 1024 + tid] - gbase], 1);
        __syncthreads();
        int c = cnt[tid];            // own bin only
        int p = (c + 1) & ~1;        // pad to even so pair-loads stay aligned
        cnt[tid] = p;                // own slot only - no race
        __syncthreads();
        // Hillis-Steele inclusive scan over 1024 bins
        for (int off = 1; off < NPG; off <<= 1) {
            int v = cnt[tid];
            int vv = (tid >= off) ? cnt[tid - off] : 0;
            __syncthreads();
            cnt[tid] = v + vv;
            __syncthreads();
        }
        int excl = cnt[tid] - p;     // exclusive prefix (even)
        offs[gbase + tid] = excl;
        deg[gbase + tid] = c;
        cur[tid] = excl;
        __syncthreads();
        unsigned short* cg = csr + (size_t)g * CSTRIDE;
#pragma unroll 4
        for (int it = 0; it < EPG / 1024; it++) {
            int e = it * 1024 + tid;
            int d = ed[e] - gbase;
            int s = es[e] - gbase;
            int pos = atomicAdd(&cur[d], 1);
            cg[pos] = (unsigned short)s;
        }
    } else {
        // ---- conversions: 2080 blocks x 1024 threads
        long idx = (long)(bid - B_G) * 1024 + tid;
        if (idx < 32768) {
            int n = (int)(idx >> 8), k = (int)(idx & 255);
            float v = (k < 128) ? Wself[k * 128 + n] : Wneigh[(k - 128) * 128 + n];
            wt[idx] = f2bf(v);
        } else if (idx < 32768 + 1048576) {
            long fi = idx - 32768;
            int g = (int)(fi >> 14), d = (int)((fi >> 7) & 127), k = (int)(fi & 127);
            feaT[fi] = f2bf(fea[((long)g * 128 + k) * 128 + d]);
        } else {
            long gi = idx - 32768 - 1048576;   // 8 floats per item
            const float4* hp = (const float4*)h + gi * 2;
            float4 a = hp[0], b4 = hp[1];
            uint4 w;
            w.x = pack2(a.x, a.y);
            w.y = pack2(a.z, a.w);
            w.z = pack2(b4.x, b4.y);
            w.w = pack2(b4.z, b4.w);
            ((uint4*)h_bf)[gi] = w;
        }
    }
}

// ================ aggregation (pull, bf16): one wave per node,
// 2 edges per gather instruction (lanes 0-31 edge A, 32-63 edge B)
__global__ __launch_bounds__(256) void agg_kernel(
    const short* __restrict__ h_bf, const unsigned short* __restrict__ csr,
    const int* __restrict__ offs, const int* __restrict__ deg,
    short* __restrict__ neigh)
{
    int g = blockIdx.x & 63;
    int chunk = blockIdx.x >> 6;
    int wave = threadIdx.x >> 6, lane = threadIdx.x & 63;
    int local = chunk * 4 + wave;
    int node = g * NPG + local;
    int start = offs[node];
    int m = deg[node];
    const unsigned short* lst = csr + (size_t)g * CSTRIDE + start;
    const uint2* rows = (const uint2*)h_bf + (size_t)g * NPG * 32;  // 32 uint2 / row
    int l31 = lane & 31;
    int hi = lane >> 5;
    float s0 = 0.f, s1 = 0.f, s2 = 0.f, s3 = 0.f;
    int pairs = m >> 1;
    int p = 0;
    for (; p + 4 <= pairs; p += 4) {
        unsigned pp[4];
#pragma unroll
        for (int u = 0; u < 4; u++) pp[u] = *(const unsigned*)(lst + 2 * (p + u));
        uint2 v[4];
#pragma unroll
        for (int u = 0; u < 4; u++) {
            int s = hi ? (int)(pp[u] >> 16) : (int)(pp[u] & 0xffff);
            v[u] = rows[s * 32 + l31];
        }
#pragma unroll
        for (int u = 0; u < 4; u++) {
            s0 += __uint_as_float(v[u].x << 16);
            s1 += __uint_as_float(v[u].x & 0xffff0000u);
            s2 += __uint_as_float(v[u].y << 16);
            s3 += __uint_as_float(v[u].y & 0xffff0000u);
        }
    }
    for (; p < pairs; p++) {
        unsigned pp = *(const unsigned*)(lst + 2 * p);
        int s = hi ? (int)(pp >> 16) : (int)(pp & 0xffff);
        uint2 vv = rows[s * 32 + l31];
        s0 += __uint_as_float(vv.x << 16);
        s1 += __uint_as_float(vv.x & 0xffff0000u);
        s2 += __uint_as_float(vv.y << 16);
        s3 += __uint_as_float(vv.y & 0xffff0000u);
    }
    if (m & 1) {
        int s = lst[m - 1];
        if (!hi) {
            uint2 vv = rows[s * 32 + l31];
            s0 += __uint_as_float(vv.x << 16);
            s1 += __uint_as_float(vv.x & 0xffff0000u);
            s2 += __uint_as_float(vv.y << 16);
            s3 += __uint_as_float(vv.y & 0xffff0000u);
        }
    }
    s0 += __shfl_xor(s0, 32, 64);
    s1 += __shfl_xor(s1, 32, 64);
    s2 += __shfl_xor(s2, 32, 64);
    s3 += __shfl_xor(s3, 32, 64);
    if (!hi) {
        float invd = 1.0f / fmaxf((float)m, 1.0f);
        uint2 w;
        w.x = pack2(s0 * invd, s1 * invd);
        w.y = pack2(s2 * invd, s3 * invd);
        ((uint2*)neigh)[(size_t)node * 32 + l31] = w;
    }
}

// ================ fused: assign = softmax(relu([h_bf|neigh] @ wt^T + b));
//                  out = assign @ fea   (P kept on-chip via LDS round-trip)
__global__ __launch_bounds__(256) void fused_kernel(
    const short* __restrict__ h_bf, const short* __restrict__ neigh,
    const short* __restrict__ wt, const float* __restrict__ bias,
    const short* __restrict__ feaT, float* __restrict__ out)
{
    __shared__ __align__(16) char smem[50688];
    short* lds_a = (short*)smem;            // phase1: 128x72
    short* lds_b = lds_a + 128 * 72;        // phase1: 128x72
    short* ldsP  = (short*)smem;            // phase2: 128x132 (overlaps phase1)
    short* ldsB2 = ldsP + 128 * 132;        // phase2: 64x132

    int tid = threadIdx.x;
    int tile_m = blockIdx.x * 128;
    int g = tile_m >> 10;
    int wave = tid >> 6, lane = tid & 63;
    int l15 = lane & 15, quad = lane >> 4;

    floatx4 zz = {0.f, 0.f, 0.f, 0.f};
    floatx4 acc[2][8];
#pragma unroll
    for (int i = 0; i < 2; i++)
#pragma unroll
        for (int j = 0; j < 8; j++) acc[i][j] = zz;

    int row_s = tid >> 1;
    int c0 = (tid & 1) * 32;

    // ---- GEMM1: logits = [h_bf | neigh] @ wt^T, K=256 in 4 chunks of 64
    for (int kk = 0; kk < 4; kk++) {
        const short* src = (kk < 2)
            ? h_bf + (size_t)(tile_m + row_s) * DIN + kk * 64 + c0
            : neigh + (size_t)(tile_m + row_s) * DIN + (kk - 2) * 64 + c0;
        short* dsta = lds_a + row_s * 72 + c0;
#pragma unroll
        for (int i = 0; i < 32; i += 8)
            *reinterpret_cast<short8*>(dsta + i) = *reinterpret_cast<const short8*>(src + i);
        const short* srcb = wt + row_s * 256 + kk * 64 + c0;
        short* dstb = lds_b + row_s * 72 + c0;
#pragma unroll
        for (int i = 0; i < 32; i += 8)
            *reinterpret_cast<short8*>(dstb + i) = *reinterpret_cast<const short8*>(srcb + i);
        __syncthreads();
#pragma unroll
        for (int ks = 0; ks < 2; ks++) {
            short8 af[2];
#pragma unroll
            for (int rb = 0; rb < 2; rb++) {
                int m = wave * 32 + rb * 16 + l15;
                af[rb] = *reinterpret_cast<const short8*>(lds_a + m * 72 + ks * 32 + quad * 8);
            }
#pragma unroll
            for (int cb = 0; cb < 8; cb++) {
                int n = cb * 16 + l15;
                short8 bf = *reinterpret_cast<const short8*>(lds_b + n * 72 + ks * 32 + quad * 8);
                acc[0][cb] = __builtin_amdgcn_mfma_f32_16x16x32_bf16(af[0], bf, acc[0][cb], 0, 0, 0);
                acc[1][cb] = __builtin_amdgcn_mfma_f32_16x16x32_bf16(af[1], bf, acc[1][cb], 0, 0, 0);
            }
        }
        __syncthreads();
    }

    // ---- softmax(relu(+bias)) in regs; P -> LDS (bf16, stride 132)
    float bv[8];
#pragma unroll
    for (int cb = 0; cb < 8; cb++) bv[cb] = bias[cb * 16 + l15];

#pragma unroll
    for (int rb = 0; rb < 2; rb++) {
#pragma unroll
        for (int v = 0; v < 4; v++) {
            float x[8];
            float m = -1e30f;
#pragma unroll
            for (int cb = 0; cb < 8; cb++) {
                float t = acc[rb][cb][v] + bv[cb];
                t = fmaxf(t, 0.f);
                x[cb] = t;
                m = fmaxf(m, t);
            }
#pragma unroll
            for (int off = 1; off < 16; off <<= 1) m = fmaxf(m, __shfl_xor(m, off, 64));
            float s = 0.f;
#pragma unroll
            for (int cb = 0; cb < 8; cb++) { x[cb] = __expf(x[cb] - m); s += x[cb]; }
#pragma unroll
            for (int off = 1; off < 16; off <<= 1) s += __shfl_xor(s, off, 64);
            float inv = 1.0f / s;
            int row = wave * 32 + rb * 16 + quad * 4 + v;   // local row
#pragma unroll
            for (int cb = 0; cb < 8; cb++)
                ldsP[row * 132 + cb * 16 + l15] = f2bf(x[cb] * inv);
        }
    }

    // ---- GEMM2: out = P @ fea[g], feaT staged in two 64-row halves
    floatx4 oacc[2][8];
#pragma unroll
    for (int i = 0; i < 2; i++)
#pragma unroll
        for (int j = 0; j < 8; j++) oacc[i][j] = zz;

    int r2 = tid >> 2;            // 0..63
    int c2 = (tid & 3) * 32;      // 0..96
    short8 pf[2][4];

    for (int half = 0; half < 2; half++) {
        if (half) __syncthreads();   // protect previous-half B reads
        const short* srcb = feaT + ((size_t)g * 128 + half * 64 + r2) * 128 + c2;
        short* dstb = ldsB2 + r2 * 132 + c2;
#pragma unroll
        for (int i = 0; i < 32; i += 8)
            *reinterpret_cast<short8*>(dstb + i) = *reinterpret_cast<const short8*>(srcb + i);
        __syncthreads();
        if (half == 0) {
#pragma unroll
            for (int rb = 0; rb < 2; rb++)
#pragma unroll
                for (int ks = 0; ks < 4; ks++)
                    pf[rb][ks] = *reinterpret_cast<const short8*>(
                        ldsP + (wave * 32 + rb * 16 + l15) * 132 + ks * 32 + quad * 8);
        }
#pragma unroll
        for (int cb2 = 0; cb2 < 4; cb2++) {
            int cb = half * 4 + cb2;
#pragma unroll
            for (int ks = 0; ks < 4; ks++) {
                short8 bf = *reinterpret_cast<const short8*>(
                    ldsB2 + (cb2 * 16 + l15) * 132 + ks * 32 + quad * 8);
                oacc[0][cb] = __builtin_amdgcn_mfma_f32_16x16x32_bf16(pf[0][ks], bf, oacc[0][cb], 0, 0, 0);
                oacc[1][cb] = __builtin_amdgcn_mfma_f32_16x16x32_bf16(pf[1][ks], bf, oacc[1][cb], 0, 0, 0);
            }
        }
    }

#pragma unroll
    for (int rb = 0; rb < 2; rb++)
#pragma unroll
        for (int v = 0; v < 4; v++) {
            int row = tile_m + wave * 32 + rb * 16 + quad * 4 + v;
#pragma unroll
            for (int cb = 0; cb < 8; cb++)
                out[(size_t)row * 128 + cb * 16 + l15] = oacc[rb][cb][v];
        }
}

extern "C" void kernel_launch(void* const* d_in, const int* in_sizes, int n_in,
                              void* d_out, int out_size, void* d_ws, size_t ws_size,
                              hipStream_t stream) {
    const float* h      = (const float*)d_in[0];
    const float* fea    = (const float*)d_in[1];
    const float* Wself  = (const float*)d_in[2];
    const float* Wneigh = (const float*)d_in[3];
    const float* bias   = (const float*)d_in[4];
    const int*   esrc   = (const int*)d_in[5];
    const int*   edst   = (const int*)d_in[6];
    float* out = (float*)d_out;

    char* ws = (char*)d_ws;
    short* h_bf = (short*)ws;
    size_t off = (size_t)N_NODES * DIN * sizeof(short);                       // 16 MB
    short* neigh = (short*)(ws + off); off += (size_t)N_NODES * DIN * sizeof(short);   // 16 MB
    short* wt    = (short*)(ws + off); off += (size_t)128 * 256 * sizeof(short);       // 64 KB
    short* feaT  = (short*)(ws + off); off += (size_t)B_G * 128 * 128 * sizeof(short); // 2 MB
    unsigned short* csr = (unsigned short*)(ws + off); off += (size_t)B_G * CSTRIDE * sizeof(short); // 2.2 MB
    int* offs = (int*)(ws + off); off += (size_t)N_NODES * sizeof(int);       // 256 KB
    int* deg  = (int*)(ws + off);                                             // 256 KB

    // setup_all grid: 64 CSR blocks + (32768 + 1048576 + 1048576)/1024 = 2080 conv blocks
    setup_all<<<B_G + 2080, 1024, 0, stream>>>(Wself, Wneigh, fea, h, esrc, edst,
                                               wt, feaT, h_bf, offs, deg, csr);
    agg_kernel<<<256 * B_G, 256, 0, stream>>>(h_bf, csr, offs, deg, neigh);
    fused_kernel<<<N_NODES / 128, 256, 0, stream>>>(h_bf, neigh, wt, bias, feaT, out);
}